// Round 7
// baseline (21653.291 us; speedup 1.0000x reference)
//
#include <hip/hip_runtime.h>
#include <hip/hip_bf16.h>

// LSTM: L=1024, B=64, I=512, H=512, fp32 in/out.
// Persistent kernel, 64 WGs x 256 thr. 8 clusters x 8 WGs; cluster = 8
// batches; WG = 64 h-idx; wave = 16 h-idx as 4 N-tiles (each N-tile = 16
// gate rows = 4 h x 4 gates, round-5 layout). Weights live in VGPRs:
// bfrag[128] = 512 B/lane = 512 KB/WG (full CU register file, 1 wave/SIMD).
// A-operand (h,x) is shared across the 4 N-tiles, so x/h load volume is
// unchanged from round 5 while the cluster shrinks 32 WGs -> 8 WGs:
// 4x fewer sync participants, 4x fewer spinning waves chip-wide.
// Exchange protocol: verbatim round-5 medium (relaxed agent-scope atomics,
// MALL-coherent — proven rounds 2/3/5). Per-wave flags, 32 per cluster.

typedef __attribute__((ext_vector_type(8))) short bf16x8;
typedef __attribute__((ext_vector_type(4))) float f32x4;

#define NT 1024
#define NB 64
#define NH 512
#define NI 512

#define FLAGS_OFF 0        // u32[8][32]  (1 KiB)
#define HX_OFF    4096     // u16[2][64][512] (128 KiB)
#define ZERO_BYTES 4096

__device__ __forceinline__ bf16x8 pack8(float4 a, float4 b) {
    union U2 { __hip_bfloat162 h; unsigned int u; } c0, c1, c2, c3;
    c0.h = __float22bfloat162_rn(make_float2(a.x, a.y));
    c1.h = __float22bfloat162_rn(make_float2(a.z, a.w));
    c2.h = __float22bfloat162_rn(make_float2(b.x, b.y));
    c3.h = __float22bfloat162_rn(make_float2(b.z, b.w));
    union R { bf16x8 v; unsigned int u[4]; } r;
    r.u[0] = c0.u; r.u[1] = c1.u; r.u[2] = c2.u; r.u[3] = c3.u;
    return r.v;
}

__device__ __forceinline__ float sigm(float v) {
    return 1.0f / (1.0f + __expf(-v));
}
__device__ __forceinline__ float tanh_f(float v) {
    float e = __expf(-2.0f * fabsf(v));        // in (0,1], no overflow
    float r = (1.0f - e) / (1.0f + e);
    return copysignf(r, v);
}

__global__ __launch_bounds__(256, 1) void lstm_fused(
    const float* __restrict__ x,
    const float* __restrict__ h0,
    const float* __restrict__ c0,
    const float* __restrict__ Wf, const float* __restrict__ Bf,
    const float* __restrict__ Wi, const float* __restrict__ Bi,
    const float* __restrict__ Wc, const float* __restrict__ Bc,
    const float* __restrict__ Wo, const float* __restrict__ Bo,
    float* __restrict__ out,
    unsigned char* __restrict__ ws)
{
    unsigned int*   flags = (unsigned int*)(ws + FLAGS_OFF);
    unsigned short* hx    = (unsigned short*)(ws + HX_OFF);

    const int tid  = threadIdx.x;
    const int wv   = tid >> 6;            // wave 0..3
    const int lane = tid & 63;
    const int n    = lane & 15;           // D col within an N-tile
    const int kg   = lane >> 4;           // k-group 0..3
    const int cl   = blockIdx.x & 7;      // cluster (round-robin -> same XCD)
    const int wg   = blockIdx.x >> 3;     // WG within cluster, 0..7

    const int g = n & 3;                  // 0=f 1=i 2=c 3=o

    const float* Wg = (g == 0) ? Wf : (g == 1) ? Wi : (g == 2) ? Wc : Wo;
    const float* Bg = (g == 0) ? Bf : (g == 1) ? Bi : (g == 2) ? Bc : Bo;

    const int m_a   = (n < 8) ? n : 7;    // A-row batch (8..15 dup)
    const int bglob = cl * 8 + m_a;

    // h-index per N-tile nt: j = wg*64 + wv*16 + nt*4 + (n>>2)
    const int jbase = (wg << 6) + (wv << 4) + (n >> 2);

    // ---- prologue: 4 N-tiles of static B-fragments (512 B/lane) ----
    bf16x8 bfrag[128];                    // [nt][kb], kb 0..15 h-part, 16..31 x
    float  bias_v[4];
    #pragma unroll
    for (int nt = 0; nt < 4; ++nt) {
        const int jnt = jbase + (nt << 2);
        const float* wrow = Wg + (size_t)jnt * (NH + NI);
        #pragma unroll
        for (int kb = 0; kb < 32; ++kb) {
            const float* p = wrow + kb * 32 + kg * 8;
            bfrag[nt * 32 + kb] = pack8(*(const float4*)(p),
                                        *(const float4*)(p + 4));
        }
        bias_v[nt] = Bg[jnt];
    }

    const bool active = (g == 0) && (kg < 2);   // 8 lanes/wave x 4 regs x 4 nt
    float Cst[16];                              // [nt*4 + r]
    #pragma unroll
    for (int nt = 0; nt < 4; ++nt)
        #pragma unroll
        for (int r = 0; r < 4; ++r)
            Cst[nt * 4 + r] = active
                ? c0[(size_t)(cl * 8 + kg * 4 + r) * NH + jbase + (nt << 2)]
                : 0.0f;

    unsigned int* fb = flags + cl * 32;         // 32 wave-flags, 128 B
    const int myflag = wg * 4 + wv;

    for (int t = 0; t < NT; ++t) {
        // -- x fragments (shared across the 4 N-tiles) + x-partial MFMAs --
        const float* xrow = x + ((size_t)t * NB + bglob) * NI;
        bf16x8 xfrag[16];
        #pragma unroll
        for (int q = 0; q < 16; ++q) {
            const float* p = xrow + q * 32 + kg * 8;
            xfrag[q] = pack8(*(const float4*)(p), *(const float4*)(p + 4));
        }
        f32x4 ax[8];                            // [nt][chain], 2 chains/nt
        #pragma unroll
        for (int nt = 0; nt < 4; ++nt) {
            ax[2 * nt]     = (f32x4){bias_v[nt], bias_v[nt], bias_v[nt], bias_v[nt]};
            ax[2 * nt + 1] = (f32x4){0.f, 0.f, 0.f, 0.f};
        }
        #pragma unroll
        for (int nt = 0; nt < 4; ++nt)
            #pragma unroll
            for (int q = 0; q < 16; q += 2) {
                ax[2 * nt]     = __builtin_amdgcn_mfma_f32_16x16x32_bf16(
                    xfrag[q],     bfrag[nt * 32 + 16 + q],     ax[2 * nt],     0, 0, 0);
                ax[2 * nt + 1] = __builtin_amdgcn_mfma_f32_16x16x32_bf16(
                    xfrag[q + 1], bfrag[nt * 32 + 16 + q + 1], ax[2 * nt + 1], 0, 0, 0);
            }

        // -- wait: all 32 producer waves of step t-1 (one u32 load/lane) --
        if (t > 0) {
            const unsigned int tgt = (unsigned int)t;
            const unsigned int* fp = fb + (lane & 31);
            int guard = 1 << 18;
            for (;;) {
                unsigned int fv = __hip_atomic_load(
                    fp, __ATOMIC_RELAXED, __HIP_MEMORY_SCOPE_AGENT);
                if (__all(fv >= tgt)) break;
                if (--guard == 0) break;          // hang safety
            }
            __builtin_amdgcn_sched_barrier(0);    // keep h-loads after spin
        }

        // -- h fragments (shared across the 4 N-tiles) --
        bf16x8 hfrag[16];
        if (t == 0) {
            const float* hrow = h0 + (size_t)bglob * NH;
            #pragma unroll
            for (int q = 0; q < 16; ++q) {
                const float* p = hrow + q * 32 + kg * 8;
                hfrag[q] = pack8(*(const float4*)(p), *(const float4*)(p + 4));
            }
        } else {
            const unsigned short* hrow =
                hx + ((size_t)((t - 1) & 1) * NB + bglob) * NH;
            #pragma unroll
            for (int q = 0; q < 16; ++q) {
                const unsigned long long* p =
                    (const unsigned long long*)(hrow + q * 32 + kg * 8);
                union { bf16x8 v; unsigned long long u[2]; } un;
                un.u[0] = __hip_atomic_load(p,     __ATOMIC_RELAXED,
                                            __HIP_MEMORY_SCOPE_AGENT);
                un.u[1] = __hip_atomic_load(p + 1, __ATOMIC_RELAXED,
                                            __HIP_MEMORY_SCOPE_AGENT);
                hfrag[q] = un.v;
            }
        }

        #pragma unroll
        for (int nt = 0; nt < 4; ++nt)
            #pragma unroll
            for (int q = 0; q < 16; q += 2) {
                ax[2 * nt]     = __builtin_amdgcn_mfma_f32_16x16x32_bf16(
                    hfrag[q],     bfrag[nt * 32 + q],     ax[2 * nt],     0, 0, 0);
                ax[2 * nt + 1] = __builtin_amdgcn_mfma_f32_16x16x32_bf16(
                    hfrag[q + 1], bfrag[nt * 32 + q + 1], ax[2 * nt + 1], 0, 0, 0);
            }

        // -- gather f/i/c/o in 4-lane groups, elementwise, h-stores --
        unsigned short* hxout = hx + (size_t)(t & 1) * NB * NH;
        float harr[16];
        #pragma unroll
        for (int nt = 0; nt < 4; ++nt) {
            f32x4 acc = ax[2 * nt] + ax[2 * nt + 1];
            const int jnt = jbase + (nt << 2);
            #pragma unroll
            for (int r = 0; r < 4; ++r) {
                float fv = acc[r];
                float iv = __shfl_xor(fv, 1);
                float gv = __shfl_xor(fv, 2);
                float ov = __shfl_xor(fv, 3);
                if (active) {
                    float ft = sigm(fv);
                    float it = sigm(iv);
                    float gt = tanh_f(gv);
                    float ot = sigm(ov);
                    float Cn = ft * Cst[nt * 4 + r] + it * gt;
                    Cst[nt * 4 + r] = Cn;
                    float ht = ot * tanh_f(Cn);
                    harr[nt * 4 + r] = ht;
                    int m = kg * 4 + r;               // batch within cluster
                    __hip_bfloat16 hb = __float2bfloat16(ht);
                    __hip_atomic_store(
                        (unsigned short*)(hxout + (size_t)(cl * 8 + m) * NH + jnt),
                        *(unsigned short*)&hb,
                        __ATOMIC_RELAXED, __HIP_MEMORY_SCOPE_AGENT);
                }
            }
        }

        // -- publish: drain h stores, then one 4B per-wave flag store --
        asm volatile("s_waitcnt vmcnt(0)" ::: "memory");
        if (lane == 0)
            __hip_atomic_store(fb + myflag, (unsigned int)(t + 1),
                               __ATOMIC_RELAXED, __HIP_MEMORY_SCOPE_AGENT);

        // -- fp32 output stores AFTER publish (off the critical path) --
        if (active) {
            #pragma unroll
            for (int nt = 0; nt < 4; ++nt)
                #pragma unroll
                for (int r = 0; r < 4; ++r)
                    out[((size_t)t * NB + cl * 8 + kg * 4 + r) * NH
                        + jbase + (nt << 2)] = harr[nt * 4 + r];
        }
    }
}

extern "C" void kernel_launch(void* const* d_in, const int* in_sizes, int n_in,
                              void* d_out, int out_size, void* d_ws, size_t ws_size,
                              hipStream_t stream) {
    const float* x  = (const float*)d_in[0];
    const float* h0 = (const float*)d_in[1];
    const float* c0 = (const float*)d_in[2];
    const float* Wf = (const float*)d_in[3];
    const float* Bf = (const float*)d_in[4];
    const float* Wi = (const float*)d_in[5];
    const float* Bi = (const float*)d_in[6];
    const float* Wc = (const float*)d_in[7];
    const float* Bc = (const float*)d_in[8];
    const float* Wo = (const float*)d_in[9];
    const float* Bo = (const float*)d_in[10];
    float* out = (float*)d_out;

    // Zero the flag array each launch (monotonic flags must restart at 0;
    // d_ws is not re-poisoned between graph replays). hx needs no init —
    // every read is gated by this launch's flags.
    hipMemsetAsync(d_ws, 0, ZERO_BYTES, stream);

    lstm_fused<<<dim3(64), dim3(256), 0, stream>>>(
        x, h0, c0, Wf, Bf, Wi, Bi, Wc, Bc, Wo, Bo, out,
        (unsigned char*)d_ws);
}

// Round 8
// 5824.054 us; speedup vs baseline: 3.7179x; 3.7179x over previous
//
#include <hip/hip_runtime.h>
#include <hip/hip_bf16.h>

// LSTM: L=1024, B=64, I=512, H=512, fp32 in/out.
// Persistent kernel, 256 WGs x 256 thr (1 WG/CU). 8 clusters x 32 WGs;
// cluster = 8 batches; wave = 16 gate rows (4 h-idx x 4 gates). Weights in
// VGPRs as MFMA B-fragments; C state in registers. Round-5 skeleton.
// ROUND-8 CHANGE: h exchange is PARITY-CODED, flags become advisory:
//   store code = h_bits ^ (((t>>1)&1) ? 0xFFFF : 0).  Valid h has |h|<=1.0
//   => bf16 exp <= 127 => bit14 == 0; inverted form has bit14 == 1. The same
//   hx slot is reused at t and t+2 whose (t>>1) parities differ, so stale
//   data (incl. cross-replay) and partial arrival are detected per-u16.
// Producer: h-stores + flag store issued back-to-back, NO vmcnt drain.
// Consumer: poll flags (cheap, 1KB), then load h and parity-validate;
//   reload on rare mismatch. Removes 2 MALL hops from the serial chain.

typedef __attribute__((ext_vector_type(8))) short bf16x8;
typedef __attribute__((ext_vector_type(4))) float f32x4;

#define NT 1024
#define NB 64
#define NH 512
#define NI 512

#define FLAGS_OFF 0        // u32[8][128]  (4 KiB)
#define HX_OFF    4096     // u16[2][64][512] (128 KiB)
#define ZERO_BYTES 4096

#define VBITS 0x4000400040004000ULL   // bit14 of each u16 lane

__device__ __forceinline__ bf16x8 pack8(float4 a, float4 b) {
    union U2 { __hip_bfloat162 h; unsigned int u; } c0, c1, c2, c3;
    c0.h = __float22bfloat162_rn(make_float2(a.x, a.y));
    c1.h = __float22bfloat162_rn(make_float2(a.z, a.w));
    c2.h = __float22bfloat162_rn(make_float2(b.x, b.y));
    c3.h = __float22bfloat162_rn(make_float2(b.z, b.w));
    union R { bf16x8 v; unsigned int u[4]; } r;
    r.u[0] = c0.u; r.u[1] = c1.u; r.u[2] = c2.u; r.u[3] = c3.u;
    return r.v;
}

__device__ __forceinline__ float sigm(float v) {
    return 1.0f / (1.0f + __expf(-v));
}
__device__ __forceinline__ float tanh_f(float v) {
    float e = __expf(-2.0f * fabsf(v));        // in (0,1], no overflow
    float r = (1.0f - e) / (1.0f + e);         // < 1 exactly in fp32
    return copysignf(r, v);
}

__global__ __launch_bounds__(256, 1) void lstm_fused(
    const float* __restrict__ x,
    const float* __restrict__ h0,
    const float* __restrict__ c0,
    const float* __restrict__ Wf, const float* __restrict__ Bf,
    const float* __restrict__ Wi, const float* __restrict__ Bi,
    const float* __restrict__ Wc, const float* __restrict__ Bc,
    const float* __restrict__ Wo, const float* __restrict__ Bo,
    float* __restrict__ out,
    unsigned char* __restrict__ ws)
{
    unsigned int*   flags = (unsigned int*)(ws + FLAGS_OFF);
    unsigned short* hx    = (unsigned short*)(ws + HX_OFF);

    const int tid  = threadIdx.x;
    const int wv   = tid >> 6;            // wave 0..3
    const int lane = tid & 63;
    const int n    = lane & 15;           // D col (gate row within wave tile)
    const int kg   = lane >> 4;           // k-group 0..3
    const int cl   = blockIdx.x & 7;      // cluster (XCD-swizzle heuristic)
    const int wg   = blockIdx.x >> 3;     // WG within cluster, 0..31

    const int jj = (wv << 2) + (n >> 2);          // 0..15 within WG
    const int j  = (wg << 4) + jj;                // global h index
    const int g  = n & 3;                         // 0=f 1=i 2=c 3=o

    const float* Wg = (g == 0) ? Wf : (g == 1) ? Wi : (g == 2) ? Wc : Wo;
    const float* Bg = (g == 0) ? Bf : (g == 1) ? Bi : (g == 2) ? Bc : Bo;

    const int m_a   = (n < 8) ? n : 7;            // A-row batch (8..15 dup)
    const int bglob = cl * 8 + m_a;

    // ---- prologue: static B-fragments (weights, bf16) into VGPRs ----
    bf16x8 bfrag[32];
    {
        const float* wrow = Wg + (size_t)j * (NH + NI);
        #pragma unroll
        for (int kb = 0; kb < 32; ++kb) {
            const float* p = wrow + kb * 32 + kg * 8;
            bfrag[kb] = pack8(*(const float4*)(p), *(const float4*)(p + 4));
        }
    }
    const float bias_v = Bg[j];

    const bool active = (g == 0) && (kg < 2);     // 8 lanes/wave x 4 regs
    float Cst[4];
    #pragma unroll
    for (int r = 0; r < 4; ++r)
        Cst[r] = active ? c0[(size_t)(cl * 8 + kg * 4 + r) * NH + j] : 0.0f;

    unsigned int* fb = flags + cl * 128;          // 128 wave-flags, 512 B
    const int myflag = wg * 4 + wv;

    for (int t = 0; t < NT; ++t) {
        // -- x fragments + x-partial MFMAs (independent of other waves) --
        const float* xrow = x + ((size_t)t * NB + bglob) * NI;
        bf16x8 xfrag[16];
        #pragma unroll
        for (int q = 0; q < 16; ++q) {
            const float* p = xrow + q * 32 + kg * 8;
            xfrag[q] = pack8(*(const float4*)(p), *(const float4*)(p + 4));
        }
        f32x4 a0 = {bias_v, bias_v, bias_v, bias_v};
        f32x4 a1 = {0.f, 0.f, 0.f, 0.f};
        f32x4 a2 = {0.f, 0.f, 0.f, 0.f};
        f32x4 a3 = {0.f, 0.f, 0.f, 0.f};
        #pragma unroll
        for (int q = 0; q < 16; q += 4) {
            a0 = __builtin_amdgcn_mfma_f32_16x16x32_bf16(xfrag[q],     bfrag[16 + q],     a0, 0, 0, 0);
            a1 = __builtin_amdgcn_mfma_f32_16x16x32_bf16(xfrag[q + 1], bfrag[16 + q + 1], a1, 0, 0, 0);
            a2 = __builtin_amdgcn_mfma_f32_16x16x32_bf16(xfrag[q + 2], bfrag[16 + q + 2], a2, 0, 0, 0);
            a3 = __builtin_amdgcn_mfma_f32_16x16x32_bf16(xfrag[q + 3], bfrag[16 + q + 3], a3, 0, 0, 0);
        }

        // -- advisory wait: all 128 producer flags (one u64 load/lane) --
        if (t > 0) {
            const unsigned int tgt = (unsigned int)t;
            const unsigned long long* fp =
                (const unsigned long long*)fb + lane;
            int guard = 1 << 20;
            for (;;) {
                unsigned long long fv = __hip_atomic_load(
                    fp, __ATOMIC_RELAXED, __HIP_MEMORY_SCOPE_AGENT);
                bool ok = ((unsigned int)fv >= tgt) &&
                          ((unsigned int)(fv >> 32) >= tgt);
                if (__all(ok)) break;
                if (--guard == 0) break;          // hang safety
                __builtin_amdgcn_s_sleep(1);
            }
            __builtin_amdgcn_sched_barrier(0);
        }

        // -- h fragments: load + parity-validate (authoritative check) --
        bf16x8 hfrag[16];
        if (t == 0) {
            const float* hrow = h0 + (size_t)bglob * NH;
            #pragma unroll
            for (int q = 0; q < 16; ++q) {
                const float* p = hrow + q * 32 + kg * 8;
                hfrag[q] = pack8(*(const float4*)(p), *(const float4*)(p + 4));
            }
        } else {
            const unsigned long long pm64 =
                (((t - 1) >> 1) & 1) ? ~0ULL : 0ULL;
            const unsigned short* hrow =
                hx + ((size_t)((t - 1) & 1) * NB + bglob) * NH;
            int guard = 1 << 16;
            for (;;) {
                unsigned long long acc = 0;
                #pragma unroll
                for (int q = 0; q < 16; ++q) {
                    const unsigned long long* p =
                        (const unsigned long long*)(hrow + q * 32 + kg * 8);
                    union { bf16x8 v; unsigned long long u[2]; } un;
                    unsigned long long w0 = __hip_atomic_load(
                        p, __ATOMIC_RELAXED, __HIP_MEMORY_SCOPE_AGENT) ^ pm64;
                    unsigned long long w1 = __hip_atomic_load(
                        p + 1, __ATOMIC_RELAXED, __HIP_MEMORY_SCOPE_AGENT) ^ pm64;
                    acc |= w0;
                    acc |= w1;
                    un.u[0] = w0;
                    un.u[1] = w1;
                    hfrag[q] = un.v;
                }
                if (__all((acc & VBITS) == 0ULL)) break;  // all words fresh
                if (--guard == 0) break;          // hang safety
            }
            __builtin_amdgcn_sched_barrier(0);
        }

        #pragma unroll
        for (int q = 0; q < 16; q += 4) {
            a0 = __builtin_amdgcn_mfma_f32_16x16x32_bf16(hfrag[q],     bfrag[q],     a0, 0, 0, 0);
            a1 = __builtin_amdgcn_mfma_f32_16x16x32_bf16(hfrag[q + 1], bfrag[q + 1], a1, 0, 0, 0);
            a2 = __builtin_amdgcn_mfma_f32_16x16x32_bf16(hfrag[q + 2], bfrag[q + 2], a2, 0, 0, 0);
            a3 = __builtin_amdgcn_mfma_f32_16x16x32_bf16(hfrag[q + 3], bfrag[q + 3], a3, 0, 0, 0);
        }
        f32x4 acc = (a0 + a1) + (a2 + a3);

        // -- gather f/i/c/o in 4-lane groups, elementwise, coded h-store --
        unsigned short* hxout = hx + (size_t)(t & 1) * NB * NH;
        const unsigned int pmask = ((t >> 1) & 1) ? 0xFFFFu : 0u;
        float harr[4];
        #pragma unroll
        for (int r = 0; r < 4; ++r) {
            float fv = acc[r];
            float iv = __shfl_xor(fv, 1);
            float gv = __shfl_xor(fv, 2);
            float ov = __shfl_xor(fv, 3);
            if (active) {
                float ft = sigm(fv);
                float it = sigm(iv);
                float gt = tanh_f(gv);
                float ot = sigm(ov);
                float Cn = ft * Cst[r] + it * gt;
                Cst[r] = Cn;
                float ht = ot * tanh_f(Cn);       // |ht| <= 1.0 in fp32
                harr[r] = ht;
                int m = kg * 4 + r;               // batch within cluster
                __hip_bfloat16 hb = __float2bfloat16(ht);
                unsigned short code =
                    (unsigned short)((*(unsigned short*)&hb) ^ pmask);
                __hip_atomic_store(
                    (unsigned short*)(hxout + (size_t)(cl * 8 + m) * NH + j),
                    code, __ATOMIC_RELAXED, __HIP_MEMORY_SCOPE_AGENT);
            }
        }

        // -- advisory flag: NO drain (parity is the real gate) --
        __builtin_amdgcn_sched_barrier(0);        // keep flag after h-stores
        if (lane == 0)
            __hip_atomic_store(fb + myflag, (unsigned int)(t + 1),
                               __ATOMIC_RELAXED, __HIP_MEMORY_SCOPE_AGENT);

        // -- fp32 output stores AFTER publish (off the critical path) --
        if (active) {
            #pragma unroll
            for (int r = 0; r < 4; ++r) {
                int m = kg * 4 + r;
                out[((size_t)t * NB + cl * 8 + m) * NH + j] = harr[r];
            }
        }
    }
}

extern "C" void kernel_launch(void* const* d_in, const int* in_sizes, int n_in,
                              void* d_out, int out_size, void* d_ws, size_t ws_size,
                              hipStream_t stream) {
    const float* x  = (const float*)d_in[0];
    const float* h0 = (const float*)d_in[1];
    const float* c0 = (const float*)d_in[2];
    const float* Wf = (const float*)d_in[3];
    const float* Bf = (const float*)d_in[4];
    const float* Wi = (const float*)d_in[5];
    const float* Bi = (const float*)d_in[6];
    const float* Wc = (const float*)d_in[7];
    const float* Bc = (const float*)d_in[8];
    const float* Wo = (const float*)d_in[9];
    const float* Bo = (const float*)d_in[10];
    float* out = (float*)d_out;

    // Zero the flag array each launch (monotonic flags must restart at 0;
    // d_ws is not re-poisoned between graph replays). hx needs NO init:
    // the per-step parity code makes stale/cross-replay data self-invalidating.
    hipMemsetAsync(d_ws, 0, ZERO_BYTES, stream);

    lstm_fused<<<dim3(256), dim3(256), 0, stream>>>(
        x, h0, c0, Wf, Bf, Wi, Bi, Wc, Bc, Wo, Bo, out,
        (unsigned char*)d_ws);
}